// Round 4
// baseline (176.381 us; speedup 1.0000x reference)
//
#include <hip/hip_runtime.h>
#include <math.h>

#define TWO_PI 6.28318530717958647692f

typedef float f4 __attribute__((ext_vector_type(4)));

// ---------------------------------------------------------------------------
// K1: cartesian -> polar sampling.  pf[b][c][a][r], one thread per element.
// 128 distinct sample points -> tap table (SoA LDS) built once per block.
// ---------------------------------------------------------------------------
__global__ __launch_bounds__(256) void k1_cart2polar(const float* __restrict__ x,
                                                     float* __restrict__ pf) {
    __shared__ float w00s[128], w01s[128], w10s[128], w11s[128];
    __shared__ int   o00s[128], o01s[128], o10s[128], o11s[128];
    int tid = threadIdx.x;
    if (tid < 128) {
        int a = tid >> 3, r = tid & 7;
        float theta = (TWO_PI * (float)a) / 16.0f;
        float rad   = ((float)r + 0.5f) / 8.0f * 64.0f;
        float ys = 63.5f + rad * sinf(theta);
        float xs = 63.5f + rad * cosf(theta);
        float y0 = floorf(ys), x0 = floorf(xs);
        float wy = ys - y0,    wx = xs - x0;
        int y0i = min(max((int)y0, 0), 127);
        int y1i = min(max((int)y0 + 1, 0), 127);
        int x0i = min(max((int)x0, 0), 127);
        int x1i = min(max((int)x0 + 1, 0), 127);
        float valid = (ys >= 0.0f && ys <= 127.0f && xs >= 0.0f && xs <= 127.0f) ? 1.0f : 0.0f;
        w00s[tid] = valid * (1.0f - wy) * (1.0f - wx);
        w01s[tid] = valid * (1.0f - wy) * wx;
        w10s[tid] = valid * wy * (1.0f - wx);
        w11s[tid] = valid * wy * wx;
        o00s[tid] = y0i * 128 + x0i;
        o01s[tid] = y0i * 128 + x1i;
        o10s[tid] = y1i * 128 + x0i;
        o11s[tid] = y1i * 128 + x1i;
    }
    __syncthreads();
    int t = blockIdx.x * 256 + tid;     // < 524288
    int bin = t & 127;
    int img = t >> 7;                   // b*256 + c
    const float* ib = x + ((size_t)img << 14);
    float v = ib[o00s[bin]] * w00s[bin]
            + ib[o01s[bin]] * w01s[bin]
            + ib[o10s[bin]] * w10s[bin]
            + ib[o11s[bin]] * w11s[bin];
    pf[t] = v;
}

// ---------------------------------------------------------------------------
// K2: grouped 3x3 conv over (A=16, R=8), zero-pad 1, groups=4.
// Output transposed: pp_t[b][bin][oc]. ic split in halves + LDS reduce.
// ---------------------------------------------------------------------------
__global__ __launch_bounds__(256) void k2_conv(const float* __restrict__ pf,
                                               const float* __restrict__ w_polar,
                                               const float* __restrict__ b_polar,
                                               float* __restrict__ pp_t) {
    __shared__ __align__(16) float pfs[64 * 180];
    __shared__ __align__(16) float red[128 * 8];
    int bid = blockIdx.x;               // 512
    int b  = bid >> 5;
    int g  = (bid >> 3) & 3;
    int ot = bid & 7;
    int tid = threadIdx.x;
    for (int i = tid; i < 64 * 180; i += 256) pfs[i] = 0.0f;
    __syncthreads();
    const float* src = pf + ((size_t)(b * 256 + g * 64) << 7);
    for (int i = tid; i < 8192; i += 256) {
        int ic = i >> 7, bin = i & 127;
        pfs[ic * 180 + ((bin >> 3) + 1) * 10 + (bin & 7) + 1] = src[i];
    }
    __syncthreads();

    int half = tid >> 7;
    int bt   = tid & 127;
    int a = bt >> 3, r = bt & 7;
    int oc0 = g * 64 + ot * 8;
    float acc[8];
    #pragma unroll
    for (int j = 0; j < 8; ++j) acc[j] = 0.0f;

    const float* wbase = w_polar + (size_t)oc0 * 576 + half * 288;
    const float* pbase = pfs + half * 32 * 180 + a * 10 + r;
    for (int ic = 0; ic < 32; ++ic) {
        float v[9];
        const float* base = pbase + ic * 180;
        #pragma unroll
        for (int dh = 0; dh < 3; ++dh)
            #pragma unroll
            for (int dw = 0; dw < 3; ++dw)
                v[dh * 3 + dw] = base[dh * 10 + dw];
        #pragma unroll
        for (int j = 0; j < 8; ++j) {
            const float* wp = wbase + j * 576 + ic * 9;
            acc[j] += wp[0]*v[0] + wp[1]*v[1] + wp[2]*v[2]
                    + wp[3]*v[3] + wp[4]*v[4] + wp[5]*v[5]
                    + wp[6]*v[6] + wp[7]*v[7] + wp[8]*v[8];
        }
    }
    if (half) {
        #pragma unroll
        for (int j = 0; j < 8; ++j) red[bt * 8 + j] = acc[j];
    }
    __syncthreads();
    if (!half) {
        float* dst = pp_t + ((size_t)((b << 7) + bt)) * 256 + oc0;
        #pragma unroll
        for (int j = 0; j < 8; ++j)
            dst[j] = acc[j] + red[bt * 8 + j] + b_polar[oc0 + j];
    }
}

// ---------------------------------------------------------------------------
// K3: q[b][bin][o] = sum_c w_attn1[o][c] * pp_t[b][bin][c]
// Coalesced staging + XOR-swizzled LDS, conflict-free both ways.
// ---------------------------------------------------------------------------
__global__ __launch_bounds__(256) void k3_proj(const float* __restrict__ pp_t,
                                               const float* __restrict__ w_attn1,
                                               float* __restrict__ q) {
    __shared__ __align__(16) float wl[16384];
    int tid = threadIdx.x;
    for (int i = tid; i < 16384; i += 256) {       // i = o*256 + c
        int o = i >> 8, c = i & 255;
        wl[(c << 6) + (o ^ (c & 31))] = w_attn1[i];
    }
    __syncthreads();
    int n = blockIdx.x * 256 + tid;     // < 131072
    int b   = n >> 13;
    int bin = (n >> 6) & 127;
    int o   = n & 63;
    const float4* pr4 = (const float4*)(pp_t + ((size_t)((b << 7) + bin)) * 256);
    float acc = 0.0f;
    #pragma unroll 8
    for (int c4 = 0; c4 < 64; ++c4) {
        float4 p = pr4[c4];
        int c = c4 << 2;
        acc += wl[( c      << 6) + (o ^ ( c      & 31))] * p.x;
        acc += wl[((c + 1) << 6) + (o ^ ((c + 1) & 31))] * p.y;
        acc += wl[((c + 2) << 6) + (o ^ ((c + 2) & 31))] * p.z;
        acc += wl[((c + 3) << 6) + (o ^ ((c + 3) & 31))] * p.w;
    }
    q[n] = acc;
}

// ---------------------------------------------------------------------------
// K4 fused: per block = (batch, 256-pixel tile).
//   1) stage q[b] swizzled in LDS, 2) compute att for the 256 pixels (1/thread)
//   into LDS, 3) each thread keeps its att float4 in a REGISTER and streams
//   64 channels of x -> out (coalesced 1KB/wave-instr, no LDS/L2 in hot loop).
// grid = 1024 (b*64 + tile), block = 256.
// ---------------------------------------------------------------------------
__global__ __launch_bounds__(256) void k4_fused(const float* __restrict__ q,
                                                const float* __restrict__ b_attn1,
                                                const float* __restrict__ w_attn2,
                                                const float* __restrict__ b_attn2,
                                                const f4* __restrict__ x4,
                                                f4* __restrict__ out4) {
    __shared__ __align__(16) float qs[8896];   // swizzled [ia][ir][o]
    __shared__ __align__(16) float b1s[64];
    __shared__ __align__(16) float w2s[64];
    __shared__ __align__(16) f4 attl[64];      // att for this 256-px tile
    int b    = blockIdx.x >> 6;
    int tile = blockIdx.x & 63;
    int tid  = threadIdx.x;
    const float* qb = q + ((size_t)b << 13);
    for (int i = tid; i < 8192; i += 256) {
        int bin = i >> 6, o = i & 63;
        qs[(bin >> 3) * 556 + (bin & 7) * 68 + o] = qb[i];
    }
    if (tid < 64) { b1s[tid] = b_attn1[tid]; w2s[tid] = w_attn2[tid]; }
    __syncthreads();
    float b2 = b_attn2[0];
    const float4* q4  = (const float4*)qs;
    const float4* b14 = (const float4*)b1s;
    const float4* w24 = (const float4*)w2s;

    {   // att for pixel p = tile*256 + tid
        int p = (tile << 8) + tid;
        int h = p >> 7, w = p & 127;
        float dy = (float)h - 63.5f;
        float dx = (float)w - 63.5f;
        float rr = sqrtf(dy * dy + dx * dx);
        float th = atan2f(dy, dx);
        if (th < 0.0f) th += TWO_PI;
        float aa = th / TWO_PI * 16.0f;
        float a0 = floorf(aa);
        float wa = aa - a0;
        int ia0 = ((int)a0) & 15;
        int ia1 = (ia0 + 1) & 15;
        float ri = rr / 64.0f * 8.0f - 0.5f;
        float r0 = floorf(ri);
        float wr = ri - r0;
        int ir0 = (int)fminf(fmaxf(r0, 0.0f), 7.0f);
        int ir1 = (int)fminf(fmaxf(r0 + 1.0f, 0.0f), 7.0f);
        float valid = (rr <= 64.0f) ? 1.0f : 0.0f;
        float w00 = valid * (1.0f - wa) * (1.0f - wr);
        float w01 = valid * (1.0f - wa) * wr;
        float w10 = valid * wa * (1.0f - wr);
        float w11 = valid * wa * wr;
        int t00 = ia0 * 139 + ir0 * 17;
        int t01 = ia0 * 139 + ir1 * 17;
        int t10 = ia1 * 139 + ir0 * 17;
        int t11 = ia1 * 139 + ir1 * 17;
        float acc = b2;
        #pragma unroll
        for (int i = 0; i < 16; ++i) {
            float4 v00 = q4[t00 + i], v01 = q4[t01 + i];
            float4 v10 = q4[t10 + i], v11 = q4[t11 + i];
            float4 bb = b14[i], ww = w24[i];
            float sx = w00 * v00.x + w01 * v01.x + w10 * v10.x + w11 * v11.x;
            float sy = w00 * v00.y + w01 * v01.y + w10 * v10.y + w11 * v11.y;
            float sz = w00 * v00.z + w01 * v01.z + w10 * v10.z + w11 * v11.z;
            float sw = w00 * v00.w + w01 * v01.w + w10 * v10.w + w11 * v11.w;
            acc += fmaxf(sx + bb.x, 0.0f) * ww.x;
            acc += fmaxf(sy + bb.y, 0.0f) * ww.y;
            acc += fmaxf(sz + bb.z, 0.0f) * ww.z;
            acc += fmaxf(sw + bb.w, 0.0f) * ww.w;
        }
        ((float*)attl)[tid] = 1.0f / (1.0f + __expf(-acc));
    }
    __syncthreads();

    // stream: lane owns float4-group (tid&63) of the tile; its att f4 in a reg.
    f4 av = attl[tid & 63];
    int ch0 = tid >> 6;                                  // 0..3
    size_t base = ((size_t)b << 20) | ((size_t)tile << 6) | (size_t)(tid & 63);
    #pragma unroll 4
    for (int c = ch0; c < 256; c += 4) {
        size_t idx = base + ((size_t)c << 12);
        out4[idx] = x4[idx] * av;
    }
}

// ---------------------------------------------------------------------------
extern "C" void kernel_launch(void* const* d_in, const int* in_sizes, int n_in,
                              void* d_out, int out_size, void* d_ws, size_t ws_size,
                              hipStream_t stream) {
    const float* x       = (const float*)d_in[0];
    const float* w_polar = (const float*)d_in[1];
    const float* b_polar = (const float*)d_in[2];
    const float* w_attn1 = (const float*)d_in[3];
    const float* b_attn1 = (const float*)d_in[4];
    const float* w_attn2 = (const float*)d_in[5];
    const float* b_attn2 = (const float*)d_in[6];
    float* out = (float*)d_out;
    float* ws  = (float*)d_ws;

    float* pf   = ws;                 // 524288 f  [b][c][a][r]
    float* pp_t = ws + 524288;        // 524288 f  [b][bin][c]
    float* q    = ws + 1048576;       // 131072 f  [b][bin][o]

    hipLaunchKernelGGL(k1_cart2polar, dim3(2048), dim3(256), 0, stream, x, pf);
    hipLaunchKernelGGL(k2_conv,       dim3(512),  dim3(256), 0, stream, pf, w_polar, b_polar, pp_t);
    hipLaunchKernelGGL(k3_proj,       dim3(512),  dim3(256), 0, stream, pp_t, w_attn1, q);
    hipLaunchKernelGGL(k4_fused,      dim3(1024), dim3(256), 0, stream,
                       q, b_attn1, w_attn2, b_attn2, (const f4*)x, (f4*)out);
}